// Round 2
// baseline (132.513 us; speedup 1.0000x reference)
//
#include <hip/hip_runtime.h>

// ConvTranspose4d: temporal valid conv (KT=3) of ConvTranspose3d(stride 2, pad 1, k=3).
// Gather form: out[co,f,od,oh,ow] = sum_{i,ci,kd,kh,kw} x[ci,f+i,id,ih,iw] * W[ci,co,i,kd,kh,kw]
//   id=(od+1-kd)/2 valid iff parity matches; all parity-valid taps in range (24->47, 48->95).
// Even coord -> 1 tap (k=1); odd coord -> 2 taps (k=0,2). No bounds checks needed.
// R2: weights staged in LDS as [tap][ci*8+co][4] (uniform ds_read_b128 broadcast),
//     bijective XCD swizzle so sibling blocks sharing an x-slab hit the same L2.

typedef float f4u __attribute__((ext_vector_type(4), aligned(4)));  // unaligned-ok out vec
typedef float f4a __attribute__((ext_vector_type(4)));              // 16B-aligned

namespace {
constexpr int T_ = 8, D_ = 24, H_ = 48, W_ = 48;
constexpr int TO = 6, DO_ = 47, HO = 95, WO = 95;
constexpr int XCS = T_ * D_ * H_ * W_;   // x channel stride
constexpr int XFS = D_ * H_ * W_;        // x frame stride
constexpr int XDS = H_ * W_;             // x depth stride
constexpr long OCS = (long)TO * DO_ * HO * WO;
constexpr int OFS = DO_ * HO * WO;
constexpr int ODS = HO * WO;
constexpr int NWG = 6 * 47 * 6;          // 1692

__global__ __launch_bounds__(192) void convt4d_kernel(
    const float* __restrict__ x, const float* __restrict__ w,
    float* __restrict__ out)
{
  __shared__ float wlds[12 * 64 * 4];    // [tapslot<=12][cico][kw pad to 4] = 12.3 KB

  // --- bijective XCD-aware swizzle (nwg % 8 != 0) ---
  constexpr int q = NWG / 8, r = NWG % 8;         // 211, 4
  const int bid = blockIdx.x;
  const int xcd = bid & 7, ii = bid >> 3;
  const int start = (xcd < r) ? xcd * (q + 1) : r * (q + 1) + (xcd - r) * q;
  const int L = start + ii;
  const int ohblk = L % 6;
  const int rest = L / 6;
  const int od = rest % 47;
  const int f = rest / 47;

  const int tid = threadIdx.x;
  const int t = tid % 12;               // ow group: owns ow in [8t, 8t+8)
  const int yy = tid / 12;              // 0..15 row within parity class
  const int ph = (ohblk >= 3) ? 1 : 0;
  const int oh = 2 * ((ohblk - 3 * ph) * 16 + yy) + ph;

  // depth taps (block-uniform)
  int nd, kd0, id0, kd1 = 0, id1 = 0;
  if ((od & 1) == 0) { nd = 1; kd0 = 1; id0 = od >> 1; }
  else               { nd = 2; kd0 = 0; id0 = (od + 1) >> 1; kd1 = 2; id1 = (od - 1) >> 1; }
  // height taps (wave-uniform: lanes within a wave share parity class)
  int nh, kh0, ih0, kh1 = 0, ih1 = 0;
  if (ph == 0) { nh = 1; kh0 = 1; ih0 = oh >> 1; }
  else         { nh = 2; kh0 = 0; ih0 = (oh + 1) >> 1; kh1 = 2; ih1 = (oh - 1) >> 1; }

  // --- cooperative weight preload: only this block's taps ---
  {
    const int kd_arr[2] = {kd0, kd1};
    const int kh_arr[2] = {kh0, kh1};
    const int nslots = 3 * nd * nh;     // <= 12
    const int total = nslots * 192;     // slots * 64 cico * 3 kw
    for (int e = tid; e < total; e += 192) {
      const int slot = e / 192;
      const int rr = e % 192;
      const int cico = rr / 3, kw = rr % 3;
      const int i_ = slot / (nd * nh);
      const int r2 = slot % (nd * nh);
      const int a = r2 / nh, b = r2 % nh;
      const int src = cico * 81 + i_ * 27 + kd_arr[a] * 9 + kh_arr[b] * 3 + kw;
      wlds[slot * 256 + cico * 4 + kw] = w[src];
    }
  }
  __syncthreads();
  if (oh >= HO) return;                 // after sync: masked threads did preload

  const int iwb = 4 * t;
  const int x4off = (t < 11) ? 4 : 0;   // avoid OOB read feeding discarded ow=95

  float acc[8][8];                       // [co][m], ow = 8t+m
  #pragma unroll
  for (int co = 0; co < 8; ++co)
    #pragma unroll
    for (int m = 0; m < 8; ++m) acc[co][m] = 0.f;

  for (int i = 0; i < 3; ++i) {
    const int fr = f + i;
    for (int a = 0; a < nd; ++a) {
      const int id = a ? id1 : id0;
      for (int b = 0; b < nh; ++b) {
        const int ih = b ? ih1 : ih0;
        const int xoff = fr * XFS + id * XDS + ih * W_ + iwb;
        const float* wbase = &wlds[((i * nd + a) * nh + b) * 256];
        #pragma unroll
        for (int ci = 0; ci < 8; ++ci) {
          const float* px = x + ci * XCS + xoff;
          const f4a xa = *(const f4a*)px;     // iw = 4t .. 4t+3 (16B aligned)
          const float xb = px[x4off];         // iw = 4t+4
          #pragma unroll
          for (int co = 0; co < 8; ++co) {
            const f4a wv = *(const f4a*)(wbase + (ci * 8 + co) * 4);  // uniform b128 broadcast
            const float w0 = wv.x, w1 = wv.y, w2 = wv.z;
            // even outputs m=0,2,4,6: kw=1
            acc[co][0] = fmaf(xa.x, w1, acc[co][0]);
            acc[co][2] = fmaf(xa.y, w1, acc[co][2]);
            acc[co][4] = fmaf(xa.z, w1, acc[co][4]);
            acc[co][6] = fmaf(xa.w, w1, acc[co][6]);
            // odd outputs m=1,3,5,7: kw=0 + kw=2
            acc[co][1] = fmaf(xa.y, w0, fmaf(xa.x, w2, acc[co][1]));
            acc[co][3] = fmaf(xa.z, w0, fmaf(xa.y, w2, acc[co][3]));
            acc[co][5] = fmaf(xa.w, w0, fmaf(xa.z, w2, acc[co][5]));
            acc[co][7] = fmaf(xb,   w0, fmaf(xa.w, w2, acc[co][7]));
          }
        }
      }
    }
  }

  const long ob = (long)f * OFS + (long)od * ODS + (long)oh * HO + 8 * t;
  #pragma unroll
  for (int co = 0; co < 8; ++co) {
    float* po = out + co * OCS + ob;
    f4u lo; lo.x = acc[co][0]; lo.y = acc[co][1]; lo.z = acc[co][2]; lo.w = acc[co][3];
    *(f4u*)po = lo;
    if (t < 11) {
      f4u hi; hi.x = acc[co][4]; hi.y = acc[co][5]; hi.z = acc[co][6]; hi.w = acc[co][7];
      *(f4u*)(po + 4) = hi;
    } else {                             // ow = 88..94 (ow=95 doesn't exist)
      po[4] = acc[co][4];
      po[5] = acc[co][5];
      po[6] = acc[co][6];
    }
  }
}
}  // namespace

extern "C" void kernel_launch(void* const* d_in, const int* in_sizes, int n_in,
                              void* d_out, int out_size, void* d_ws, size_t ws_size,
                              hipStream_t stream) {
  const float* x = (const float*)d_in[0];
  const float* w = (const float*)d_in[1];
  float* out = (float*)d_out;
  hipLaunchKernelGGL(convt4d_kernel, dim3(NWG), dim3(192), 0, stream, x, w, out);
}

// Round 3
// 84.322 us; speedup vs baseline: 1.5715x; 1.5715x over previous
//
#include <hip/hip_runtime.h>

// ConvTranspose4d: temporal valid conv (KT=3) of ConvTranspose3d(stride 2, pad 1, k=3).
// Gather form: out[co,f,od,oh,ow] = sum_{i,ci,kd,kh,kw} x[ci,f+i,id,ih,iw] * W[ci,co,i,kd,kh,kw]
//   id=(od+1-kd)/2 valid iff parity matches; all parity-valid taps in range (24->47, 48->95).
// Even coord -> 1 tap (k=1); odd coord -> 2 taps (k=0,2). No bounds checks needed.
// R3 = R1 structure (scalar-pipe s_load weights via readfirstlane base; vec4 x loads;
//      8co x 8ow acc tile) + R2's bijective XCD swizzle (FETCH 75->17MB proven).
//      R2's LDS weight staging REVERTED: it moved weights off the scalar pipe onto
//      lgkm + VGPRs (68->140) and halved occupancy. // VGPR~68, SGPR~112 expected.

typedef float f4u __attribute__((ext_vector_type(4), aligned(4)));  // unaligned-ok out vec
typedef float f4a __attribute__((ext_vector_type(4)));              // 16B-aligned

namespace {
constexpr int T_ = 8, D_ = 24, H_ = 48, W_ = 48;
constexpr int TO = 6, DO_ = 47, HO = 95, WO = 95;
constexpr int XCS = T_ * D_ * H_ * W_;   // x channel stride
constexpr int XFS = D_ * H_ * W_;        // x frame stride
constexpr int XDS = H_ * W_;             // x depth stride
constexpr long OCS = (long)TO * DO_ * HO * WO;
constexpr int OFS = DO_ * HO * WO;
constexpr int ODS = HO * WO;
constexpr int NWG = 6 * 47 * 6;          // 1692

__global__ __launch_bounds__(192) void convt4d_kernel(
    const float* __restrict__ x, const float* __restrict__ w,
    float* __restrict__ out)
{
  // --- bijective XCD-aware swizzle (NWG % 8 != 0): consecutive L share the
  // same (f,od) x-slab -> same XCD L2 chunk ---
  constexpr int q = NWG / 8, r = NWG % 8;         // 211, 4
  const int bid = blockIdx.x;
  const int xcd = bid & 7, ii = bid >> 3;
  const int start = (xcd < r) ? xcd * (q + 1) : r * (q + 1) + (xcd - r) * q;
  const int L = start + ii;
  const int ohblk = L % 6;               // fastest: 6 parity-blocks of one (od,f) slab
  const int rest = L / 6;
  const int od = rest % 47;
  const int f = rest / 47;

  const int tid = threadIdx.x;
  const int t = tid % 12;                // ow group: owns ow in [8t, 8t+8)
  const int yy = tid / 12;               // 0..15 row within parity class
  const int ph = (ohblk >= 3) ? 1 : 0;   // block-uniform parity
  const int oh = 2 * ((ohblk - 3 * ph) * 16 + yy) + ph;
  if (oh >= HO) return;                  // only odd-class last block masks

  // depth taps (block-uniform)
  int nd, kd0, id0, kd1 = 0, id1 = 0;
  if ((od & 1) == 0) { nd = 1; kd0 = 1; id0 = od >> 1; }
  else               { nd = 2; kd0 = 0; id0 = (od + 1) >> 1; kd1 = 2; id1 = (od - 1) >> 1; }
  // height taps (block-uniform parity class)
  int nh, kh0, ih0, kh1 = 0, ih1 = 0;
  if (ph == 0) { nh = 1; kh0 = 1; ih0 = oh >> 1; }
  else         { nh = 2; kh0 = 0; ih0 = (oh + 1) >> 1; kh1 = 2; ih1 = (oh - 1) >> 1; }

  const int iwb = 4 * t;
  const int x4off = (t < 11) ? 4 : 0;    // avoid OOB read feeding discarded ow=95

  float acc[8][8];                        // [co][m], ow = 8t+m
  #pragma unroll
  for (int co = 0; co < 8; ++co)
    #pragma unroll
    for (int m = 0; m < 8; ++m) acc[co][m] = 0.f;

  for (int i = 0; i < 3; ++i) {
    const int fr = f + i;
    for (int a = 0; a < nd; ++a) {
      const int kd = a ? kd1 : kd0;
      const int id = a ? id1 : id0;
      for (int b = 0; b < nh; ++b) {
        const int kh = b ? kh1 : kh0;
        const int ih = b ? ih1 : ih0;
        const int xoff = fr * XFS + id * XDS + ih * W_ + iwb;
        // force weight base into SGPR -> compiler emits s_load (scalar pipe, K$)
        const int wb0 = __builtin_amdgcn_readfirstlane(i * 27 + kd * 9 + kh * 3);
        #pragma unroll
        for (int ci = 0; ci < 8; ++ci) {
          const float* px = x + ci * XCS + xoff;
          const f4a xa = *(const f4a*)px;     // iw = 4t .. 4t+3 (16B aligned)
          const float xb = px[x4off];         // iw = 4t+4 (feeds odd m=7 via kw=0)
          #pragma unroll
          for (int co = 0; co < 8; ++co) {
            const int wb = wb0 + (ci * 8 + co) * 81;  // W[ci][co][i][kd][kh][kw]
            const float w0 = w[wb + 0];
            const float w1 = w[wb + 1];
            const float w2 = w[wb + 2];
            // even outputs m=0,2,4,6: kw=1, iw=4t+m/2
            acc[co][0] = fmaf(xa.x, w1, acc[co][0]);
            acc[co][2] = fmaf(xa.y, w1, acc[co][2]);
            acc[co][4] = fmaf(xa.z, w1, acc[co][4]);
            acc[co][6] = fmaf(xa.w, w1, acc[co][6]);
            // odd outputs m=1,3,5,7: kw=0 (iw=4t+(m+1)/2) + kw=2 (iw=4t+(m-1)/2)
            acc[co][1] = fmaf(xa.y, w0, fmaf(xa.x, w2, acc[co][1]));
            acc[co][3] = fmaf(xa.z, w0, fmaf(xa.y, w2, acc[co][3]));
            acc[co][5] = fmaf(xa.w, w0, fmaf(xa.z, w2, acc[co][5]));
            acc[co][7] = fmaf(xb,   w0, fmaf(xa.w, w2, acc[co][7]));
          }
        }
      }
    }
  }

  const long ob = (long)f * OFS + (long)od * ODS + (long)oh * HO + 8 * t;
  #pragma unroll
  for (int co = 0; co < 8; ++co) {
    float* po = out + co * OCS + ob;
    f4u lo; lo.x = acc[co][0]; lo.y = acc[co][1]; lo.z = acc[co][2]; lo.w = acc[co][3];
    *(f4u*)po = lo;
    if (t < 11) {
      f4u hi; hi.x = acc[co][4]; hi.y = acc[co][5]; hi.z = acc[co][6]; hi.w = acc[co][7];
      *(f4u*)(po + 4) = hi;
    } else {                              // ow = 88..94 (ow=95 doesn't exist)
      po[4] = acc[co][4];
      po[5] = acc[co][5];
      po[6] = acc[co][6];
    }
  }
}
}  // namespace

extern "C" void kernel_launch(void* const* d_in, const int* in_sizes, int n_in,
                              void* d_out, int out_size, void* d_ws, size_t ws_size,
                              hipStream_t stream) {
  const float* x = (const float*)d_in[0];
  const float* w = (const float*)d_in[1];
  float* out = (float*)d_out;
  hipLaunchKernelGGL(convt4d_kernel, dim3(NWG), dim3(192), 0, stream, x, w, out);
}

// Round 4
// 73.714 us; speedup vs baseline: 1.7977x; 1.1439x over previous
//
#include <hip/hip_runtime.h>

// ConvTranspose4d: temporal valid conv (KT=3) of ConvTranspose3d(stride 2, pad 1, k=3).
// Gather form: out[co,f,od,oh,ow] = sum_{i,ci,kd,kh,kw} x[ci,f+i,id,ih,iw] * W[ci,co,i,kd,kh,kw]
//   id=(od+1-kd)/2 valid iff parity matches; all parity-valid taps in range (24->47, 48->95).
// Even coord -> 1 tap (k=1); odd coord -> 2 taps (k=0,2).
// R4: (1) parity-class specialization via template<ND,NH,NOW> -- all tap geometry and
//     weight offsets become compile-time immediates off an SGPR base, so the scalar
//     loads pipeline far ahead of the FMAs (R3 post-mortem: runtime wb0 blocked this);
//     (2) odd-odd class (12 taps/thread) split to 4 ow/thread -> per-wave work spread
//     4x -> 2x, fixing the low-occupancy tail (measured 16.6% == imbalance model).
//     XCD swizzle dropped: R1/R3 A/B proved FETCH 75->22MB is worth 0 time.

typedef float f4u __attribute__((ext_vector_type(4), aligned(4)));  // unaligned-ok out vec
typedef float f4a __attribute__((ext_vector_type(4)));              // 16B-aligned
typedef float f2a __attribute__((ext_vector_type(2)));              // 8B-aligned

namespace {
constexpr int T_ = 8, D_ = 24, H_ = 48, W_ = 48;
constexpr int TO = 6, DO_ = 47, HO = 95, WO = 95;
constexpr int XCS = T_ * D_ * H_ * W_;
constexpr int XFS = D_ * H_ * W_;
constexpr int XDS = H_ * W_;
constexpr long OCS = (long)TO * DO_ * HO * WO;
constexpr int OFS = DO_ * HO * WO;
constexpr int ODS = HO * WO;

// Segments: S0 = od odd & oh odd (12 taps, 4 ow/thread), S1 = od odd & oh even,
// S2 = od even & oh odd, S3 = od even & oh even.  Grid = 828+414+432+432 = 2106.
constexpr int S0_END = 828, S1_END = 1242, S2_END = 1674, NWG = 2106;

template<int ND, int NH, int NOW>
__device__ __forceinline__ void conv_body(
    const float* __restrict__ x, const float* __restrict__ w,
    float* __restrict__ out, int f, int od, int oh, int t)
{
  const int iwb = (NOW == 8 ? 4 : 2) * t;
  const int TMAX = (NOW == 8) ? 11 : 23;
  const int xext = (t < TMAX) ? (NOW / 2) : 0;  // clamp: extra elem feeds only discarded ow=95

  float acc[8][NOW];
  #pragma unroll
  for (int co = 0; co < 8; ++co)
    #pragma unroll
    for (int m = 0; m < NOW; ++m) acc[co][m] = 0.f;

  #pragma unroll 1
  for (int ci = 0; ci < 8; ++ci) {
    // SGPR base; ALL weight offsets below are compile-time immediates from here.
    const float* pw = w + __builtin_amdgcn_readfirstlane(ci * 648);
    const float* pxc = x + ci * XCS + iwb;
    #pragma unroll
    for (int i = 0; i < 3; ++i) {
      #pragma unroll
      for (int a = 0; a < ND; ++a) {
        const int KD = (ND == 1) ? 1 : (a == 0 ? 0 : 2);
        const int id = (ND == 1) ? (od >> 1) : (a == 0 ? ((od + 1) >> 1) : ((od - 1) >> 1));
        #pragma unroll
        for (int b = 0; b < NH; ++b) {
          const int KH = (NH == 1) ? 1 : (b == 0 ? 0 : 2);
          const int ih = (NH == 1) ? (oh >> 1) : (b == 0 ? ((oh + 1) >> 1) : ((oh - 1) >> 1));
          const int WOFF = i * 27 + KD * 9 + KH * 3;   // compile-time
          const float* px = pxc + (f + i) * XFS + id * XDS + ih * W_;
          if (NOW == 8) {
            const f4a xa = *(const f4a*)px;            // iw = 4t..4t+3 (16B aligned)
            const float xb = px[xext];                 // iw = 4t+4
            #pragma unroll
            for (int co = 0; co < 8; ++co) {
              const float w0 = pw[co * 81 + WOFF + 0];
              const float w1 = pw[co * 81 + WOFF + 1];
              const float w2 = pw[co * 81 + WOFF + 2];
              acc[co][0] = fmaf(xa.x, w1, acc[co][0]);
              acc[co][2] = fmaf(xa.y, w1, acc[co][2]);
              acc[co][4] = fmaf(xa.z, w1, acc[co][4]);
              acc[co][6] = fmaf(xa.w, w1, acc[co][6]);
              acc[co][1] = fmaf(xa.y, w0, fmaf(xa.x, w2, acc[co][1]));
              acc[co][3] = fmaf(xa.z, w0, fmaf(xa.y, w2, acc[co][3]));
              acc[co][5] = fmaf(xa.w, w0, fmaf(xa.z, w2, acc[co][5]));
              acc[co][7] = fmaf(xb,   w0, fmaf(xa.w, w2, acc[co][7]));
            }
          } else {
            const f2a xa = *(const f2a*)px;            // iw = 2t, 2t+1 (8B aligned)
            const float x0 = xa.x, x1 = xa.y;
            const float xb = px[xext];                 // iw = 2t+2
            #pragma unroll
            for (int co = 0; co < 8; ++co) {
              const float w0 = pw[co * 81 + WOFF + 0];
              const float w1 = pw[co * 81 + WOFF + 1];
              const float w2 = pw[co * 81 + WOFF + 2];
              acc[co][0] = fmaf(x0, w1, acc[co][0]);
              acc[co][2] = fmaf(x1, w1, acc[co][2]);
              acc[co][1] = fmaf(x1, w0, fmaf(x0, w2, acc[co][1]));
              acc[co][3] = fmaf(xb, w0, fmaf(x1, w2, acc[co][3]));
            }
          }
        }
      }
    }
  }

  const long ob = (long)f * OFS + (long)od * ODS + (long)oh * HO + NOW * t;
  #pragma unroll
  for (int co = 0; co < 8; ++co) {
    float* po = out + co * OCS + ob;
    if (NOW == 8) {
      f4u lo; lo.x = acc[co][0]; lo.y = acc[co][1]; lo.z = acc[co][2]; lo.w = acc[co][3];
      *(f4u*)po = lo;
      if (t < 11) {
        f4u hi; hi.x = acc[co][4]; hi.y = acc[co][5]; hi.z = acc[co][6]; hi.w = acc[co][7];
        *(f4u*)(po + 4) = hi;
      } else {                         // ow = 88..94 (ow=95 doesn't exist)
        po[4] = acc[co][4]; po[5] = acc[co][5]; po[6] = acc[co][6];
      }
    } else {
      if (t < 23) {
        f4u v; v.x = acc[co][0]; v.y = acc[co][1]; v.z = acc[co][2]; v.w = acc[co][3];
        *(f4u*)po = v;
      } else {                         // ow = 92..94 (ow=95 doesn't exist)
        po[0] = acc[co][0]; po[1] = acc[co][1]; po[2] = acc[co][2];
      }
    }
  }
}

__global__ __launch_bounds__(192) void convt4d_kernel(
    const float* __restrict__ x, const float* __restrict__ w,
    float* __restrict__ out)
{
  const int tid = threadIdx.x;
  const int bid = blockIdx.x;
  if (bid < S0_END) {                          // od odd, oh odd: 4 ow/thread
    const int ohb = bid % 6; const int rest = bid / 6;
    const int dd = rest % 23; const int f = rest / 23;
    const int od = 2 * dd + 1;
    const int t = tid % 24, yy = tid / 24;     // 24 ow-groups x 8 rows
    const int row = ohb * 8 + yy; if (row >= 47) return;
    const int oh = 2 * row + 1;
    conv_body<2, 2, 4>(x, w, out, f, od, oh, t);
  } else if (bid < S1_END) {                   // od odd, oh even
    const int b2 = bid - S0_END;
    const int ohb = b2 % 3; const int rest = b2 / 3;
    const int dd = rest % 23; const int f = rest / 23;
    const int od = 2 * dd + 1;
    const int t = tid % 12, yy = tid / 12;
    const int oh = 2 * (ohb * 16 + yy);
    conv_body<2, 1, 8>(x, w, out, f, od, oh, t);
  } else if (bid < S2_END) {                   // od even, oh odd
    const int b2 = bid - S1_END;
    const int ohb = b2 % 3; const int rest = b2 / 3;
    const int dd = rest % 24; const int f = rest / 24;
    const int od = 2 * dd;
    const int t = tid % 12, yy = tid / 12;
    const int row = ohb * 16 + yy; if (row >= 47) return;
    const int oh = 2 * row + 1;
    conv_body<1, 2, 8>(x, w, out, f, od, oh, t);
  } else {                                     // od even, oh even
    const int b2 = bid - S2_END;
    const int ohb = b2 % 3; const int rest = b2 / 3;
    const int dd = rest % 24; const int f = rest / 24;
    const int od = 2 * dd;
    const int t = tid % 12, yy = tid / 12;
    const int oh = 2 * (ohb * 16 + yy);
    conv_body<1, 1, 8>(x, w, out, f, od, oh, t);
  }
}
}  // namespace

extern "C" void kernel_launch(void* const* d_in, const int* in_sizes, int n_in,
                              void* d_out, int out_size, void* d_ws, size_t ws_size,
                              hipStream_t stream) {
  const float* x = (const float*)d_in[0];
  const float* w = (const float*)d_in[1];
  float* out = (float*)d_out;
  hipLaunchKernelGGL(convt4d_kernel, dim3(NWG), dim3(192), 0, stream, x, w, out);
}